// Round 1
// baseline (1062.127 us; speedup 1.0000x reference)
//
#include <hip/hip_runtime.h>
#include <hip/hip_bf16.h>

#define BB   131072
#define CC   16
#define DIN  256
#define DH   1024
#define DOUT 256
#define TM   128   // tokens per tile

typedef __attribute__((ext_vector_type(8))) short bf16x8;
typedef __attribute__((ext_vector_type(4))) float f32x4;
typedef __attribute__((ext_vector_type(4))) float float4v;

__device__ inline unsigned short f2b(float f) {
  union { float f; unsigned u; } v; v.f = f;
  unsigned u = v.u;
  return (unsigned short)((u + 0x7fffu + ((u >> 16) & 1u)) >> 16);  // RNE
}

__device__ inline void gload_lds16(const void* g, void* l) {
  __builtin_amdgcn_global_load_lds(
      (const __attribute__((address_space(1))) void*)g,
      (__attribute__((address_space(3))) void*)l, 16, 0, 0);
}

#define MFMA16(a, b, c) __builtin_amdgcn_mfma_f32_16x16x32_bf16((a), (b), (c), 0, 0, 0)

// ---------------- bucketing ----------------
__global__ void count_k(const int* __restrict__ cat, int* cnt) {
  int i = blockIdx.x * blockDim.x + threadIdx.x;
  if (i < BB) atomicAdd(&cnt[cat[i]], 1);
}

__global__ void offsets_k(const int* __restrict__ counts, int* padoff) {
  if (threadIdx.x == 0 && blockIdx.x == 0) {
    int acc = 0;
    for (int c = 0; c < CC; c++) {
      padoff[c] = acc;
      acc += ((counts[c] + TM - 1) / TM) * TM;
    }
    padoff[CC] = acc;
  }
}

__global__ void scatter_k(const int* __restrict__ cat, const int* __restrict__ padoff,
                          int* cursors, int* __restrict__ idx) {
  int i = blockIdx.x * blockDim.x + threadIdx.x;
  if (i < BB) {
    int c = cat[i];
    int pos = atomicAdd(&cursors[c], 1);
    idx[padoff[c] + pos] = i;
  }
}

// ---------------- weight conversion (f32 -> bf16, transposed [c][n][k], pre-swizzled) ----------------
// W1 src: [c][k=256][n=1024] -> dst rows (c*1024+n)*512 bytes, chunk byte (k*2)^((n&7)<<4)
__global__ void conv_w1_k(const float* __restrict__ W1, short* __restrict__ w1b) {
  int t = blockIdx.x * blockDim.x + threadIdx.x;   // 524288 threads
  int n = t & 1023;
  int j = (t >> 10) & 31;   // k-chunk of 8
  int c = t >> 15;
  const float* src = W1 + (size_t)c * 256 * 1024;
  bf16x8 o;
#pragma unroll
  for (int i = 0; i < 8; i++)
    o[i] = (short)f2b(src[(size_t)(j * 8 + i) * 1024 + n]);
  char* dst = (char*)w1b + (size_t)(c * 1024 + n) * 512 + ((j * 16) ^ ((n & 7) << 4));
  *(bf16x8*)dst = o;
}

// W2 src: [c][k=1024][n=256] -> dst rows (c*256+n)*2048 bytes, chunk byte (k*2)^((n&7)<<4)
__global__ void conv_w2_k(const float* __restrict__ W2, short* __restrict__ w2b) {
  int t = blockIdx.x * blockDim.x + threadIdx.x;   // 524288 threads
  int n = t & 255;
  int j = (t >> 8) & 127;   // k-chunk of 8
  int c = t >> 15;
  const float* src = W2 + (size_t)c * 1024 * 256;
  bf16x8 o;
#pragma unroll
  for (int i = 0; i < 8; i++)
    o[i] = (short)f2b(src[(size_t)(j * 8 + i) * 256 + n]);
  char* dst = (char*)w2b + (size_t)(c * 256 + n) * 2048 + ((j * 16) ^ ((n & 7) << 4));
  *(bf16x8*)dst = o;
}

// ---------------- fused routed MLP ----------------
// wg: 512 thr (8 waves, 4x2 wave grid), tile = 128 tokens.
// loop 16 hidden blocks of 64: L1 [128x256]x[256x64] -> relu -> hs ; L2 acc += [128x64]x[64x256]
__launch_bounds__(512, 2)
__global__ void mlp_k(const float* __restrict__ x,
                      const float* __restrict__ b1,
                      const float* __restrict__ b2,
                      const short* __restrict__ w1b,
                      const short* __restrict__ w2b,
                      const int* __restrict__ idx,
                      const int* __restrict__ padoff,
                      const int* __restrict__ counts,
                      float* __restrict__ out) {
  __shared__ __align__(16) short xs[TM * 256];   // 64 KB, [r][k] rows 512B, swz ((r&7)<<4)
  __shared__ __align__(16) short w1s[64 * 256];  // 32 KB, [n][k] rows 512B, swz ((n&7)<<4)
  __shared__ __align__(16) short w2s[256 * 64];  // 32 KB, [n][kloc] rows 128B, swz ((n&7)<<4)
  __shared__ __align__(16) short hs[TM * 64];    // 16 KB, [r][kloc] rows 128B, swz ((r&7)<<4)
  __shared__ int toks[TM];

  const int p = blockIdx.x * TM;                 // padded global position
  const int total = padoff[CC];
  if (p >= total) return;
  int c = 0;
  while (padoff[c + 1] <= p) c++;
  const int cnt = counts[c];
  const int start = p - padoff[c];

  const int tid  = threadIdx.x;
  const int lane = tid & 63;
  const int w    = tid >> 6;   // 0..7
  const int wm   = w >> 1;     // 0..3  (M: 32 rows each)
  const int wn   = w & 1;      // 0..1
  const int lrow = lane & 15;
  const int lgrp = lane >> 4;

  // ---- stage x tile (gather, f32 -> bf16) + toks ----
  {
    const int r = tid >> 2;      // 0..127
    const int q = tid & 3;       // column quarter (64 f32 each)
    const int pos = start + r;
    int tok = -1;
    if (pos < cnt) tok = idx[p + r];
    if (q == 0) toks[r] = tok;
    const int swz = (r & 7) << 4;
    char* rowbase = (char*)xs + r * 512;
    if (tok >= 0) {
      const float4v* src = (const float4v*)(x + (size_t)tok * DIN) + q * 16;
#pragma unroll
      for (int j = 0; j < 8; j++) {
        float4v v0 = src[2 * j];
        float4v v1 = src[2 * j + 1];
        bf16x8 o;
        o[0] = (short)f2b(v0[0]); o[1] = (short)f2b(v0[1]);
        o[2] = (short)f2b(v0[2]); o[3] = (short)f2b(v0[3]);
        o[4] = (short)f2b(v1[0]); o[5] = (short)f2b(v1[1]);
        o[6] = (short)f2b(v1[2]); o[7] = (short)f2b(v1[3]);
        *(bf16x8*)(rowbase + ((q * 128 + j * 16) ^ swz)) = o;
      }
    } else {
      bf16x8 z = {0, 0, 0, 0, 0, 0, 0, 0};
#pragma unroll
      for (int j = 0; j < 8; j++)
        *(bf16x8*)(rowbase + ((q * 128 + j * 16) ^ swz)) = z;
    }
  }
  __syncthreads();

  f32x4 acc2[2][8];
#pragma unroll
  for (int mi = 0; mi < 2; mi++)
#pragma unroll
    for (int ni = 0; ni < 8; ni++)
      acc2[mi][ni] = (f32x4){0.f, 0.f, 0.f, 0.f};

  const char* w1g = (const char*)w1b + (size_t)c * 1024 * 512;
  const char* w2g = (const char*)w2b + (size_t)c * 256 * 2048;

  for (int hb = 0; hb < 16; hb++) {
    // ---- stage W1 block (contiguous 32KB) + W2 block (strided rows) ----
    {
      const char* src1 = w1g + (size_t)hb * 32768;
#pragma unroll
      for (int i = 0; i < 4; i++) {
        int chunk = (w * 4 + i) * 1024;
        gload_lds16(src1 + chunk + lane * 16, (char*)w1s + chunk);
      }
#pragma unroll
      for (int i = 0; i < 4; i++) {
        int o = (w * 4 + i) * 1024 + lane * 16;
        int n = o >> 7;          // 128 B per n-row
        int q = o & 127;
        gload_lds16(w2g + (size_t)n * 2048 + hb * 128 + q, (char*)w2s + (w * 4 + i) * 1024);
      }
    }
    asm volatile("s_waitcnt vmcnt(0)" ::: "memory");
    __syncthreads();

    // ---- layer 1: acc1 = x_tile @ W1blk ----
    f32x4 acc1[2][2];
#pragma unroll
    for (int mi = 0; mi < 2; mi++)
#pragma unroll
      for (int ni = 0; ni < 2; ni++)
        acc1[mi][ni] = (f32x4){0.f, 0.f, 0.f, 0.f};

#pragma unroll
    for (int ks = 0; ks < 8; ks++) {
      const int kb = ks * 64 + lgrp * 16;
      bf16x8 a[2], bf[2];
#pragma unroll
      for (int mi = 0; mi < 2; mi++) {
        int r = wm * 32 + mi * 16 + lrow;
        a[mi] = *(const bf16x8*)((const char*)xs + r * 512 + (kb ^ ((r & 7) << 4)));
      }
#pragma unroll
      for (int ni = 0; ni < 2; ni++) {
        int n = wn * 32 + ni * 16 + lrow;
        bf[ni] = *(const bf16x8*)((const char*)w1s + n * 512 + (kb ^ ((n & 7) << 4)));
      }
#pragma unroll
      for (int mi = 0; mi < 2; mi++)
#pragma unroll
        for (int ni = 0; ni < 2; ni++)
          acc1[mi][ni] = MFMA16(a[mi], bf[ni], acc1[mi][ni]);
    }

    // ---- bias + relu -> hs (bf16) ----
#pragma unroll
    for (int mi = 0; mi < 2; mi++) {
#pragma unroll
      for (int ni = 0; ni < 2; ni++) {
        int ncol = wn * 32 + ni * 16 + lrow;   // 0..63
        float b1v = b1[(size_t)c * DH + hb * 64 + ncol];
#pragma unroll
        for (int jj = 0; jj < 4; jj++) {
          int r = wm * 32 + mi * 16 + lgrp * 4 + jj;
          float v = acc1[mi][ni][jj] + b1v;
          v = fmaxf(v, 0.0f);
          *(short*)((char*)hs + r * 128 + ((ncol * 2) ^ ((r & 7) << 4))) = (short)f2b(v);
        }
      }
    }
    __syncthreads();

    // ---- layer 2: acc2 += hs @ W2blk ----
#pragma unroll
    for (int ks = 0; ks < 2; ks++) {
      const int kb = ks * 64 + lgrp * 16;
      bf16x8 a[2];
#pragma unroll
      for (int mi = 0; mi < 2; mi++) {
        int r = wm * 32 + mi * 16 + lrow;
        a[mi] = *(const bf16x8*)((const char*)hs + r * 128 + (kb ^ ((r & 7) << 4)));
      }
#pragma unroll
      for (int ni = 0; ni < 8; ni++) {
        int n = wn * 128 + ni * 16 + lrow;    // 0..255
        bf16x8 bf = *(const bf16x8*)((const char*)w2s + n * 128 + (kb ^ ((n & 7) << 4)));
#pragma unroll
        for (int mi = 0; mi < 2; mi++)
          acc2[mi][ni] = MFMA16(a[mi], bf, acc2[mi][ni]);
      }
    }
    __syncthreads();
  }

  // ---- epilogue: + b2, scatter to out ----
#pragma unroll
  for (int ni = 0; ni < 8; ni++) {
    int col = wn * 128 + ni * 16 + lrow;
    float b2v = b2[(size_t)c * DOUT + col];
#pragma unroll
    for (int mi = 0; mi < 2; mi++) {
#pragma unroll
      for (int jj = 0; jj < 4; jj++) {
        int r = wm * 32 + mi * 16 + lgrp * 4 + jj;
        int tok = toks[r];
        if (tok >= 0) out[(size_t)tok * DOUT + col] = acc2[mi][ni][jj] + b2v;
      }
    }
  }
}

extern "C" void kernel_launch(void* const* d_in, const int* in_sizes, int n_in,
                              void* d_out, int out_size, void* d_ws, size_t ws_size,
                              hipStream_t stream) {
  (void)in_sizes; (void)n_in; (void)out_size; (void)ws_size;
  const float* x   = (const float*)d_in[0];
  const int*   cat = (const int*)d_in[1];
  const float* W1  = (const float*)d_in[2];
  const float* b1  = (const float*)d_in[3];
  const float* W2  = (const float*)d_in[4];
  const float* b2  = (const float*)d_in[5];
  float* out = (float*)d_out;

  char* ws = (char*)d_ws;
  int* counts  = (int*)(ws);
  int* cursors = (int*)(ws + 64);
  int* padoff  = (int*)(ws + 128);
  int* idx     = (int*)(ws + 1024);                     // (BB + CC*TM) ints
  short* w1b   = (short*)(ws + (1 << 20));              // 8 MB  [c][n=1024][k=256] bf16 swz
  short* w2b   = (short*)(ws + (1 << 20) + 8388608);    // 8 MB  [c][n=256][k=1024] bf16 swz

  hipMemsetAsync(d_ws, 0, 1024, stream);
  count_k<<<BB / 256, 256, 0, stream>>>(cat, counts);
  offsets_k<<<1, 64, 0, stream>>>(counts, padoff);
  scatter_k<<<BB / 256, 256, 0, stream>>>(cat, padoff, cursors, idx);
  conv_w1_k<<<2048, 256, 0, stream>>>(W1, w1b);
  conv_w2_k<<<2048, 256, 0, stream>>>(W2, w2b);

  const int ntiles = BB / TM + CC;   // upper bound incl. per-category padding
  mlp_k<<<ntiles, 512, 0, stream>>>(x, b1, b2, w1b, w2b, idx, padoff, counts, out);
}

// Round 2
// 357.302 us; speedup vs baseline: 2.9726x; 2.9726x over previous
//
#include <hip/hip_runtime.h>
#include <hip/hip_bf16.h>

#define BB   131072
#define CC   16
#define DIN  256
#define DH   1024
#define DOUT 256
#define TM   128   // tokens per tile
#define NB   512   // bucketing blocks (BB/NB = 256 tokens each)

typedef __attribute__((ext_vector_type(8))) short bf16x8;
typedef __attribute__((ext_vector_type(4))) float f32x4;
typedef __attribute__((ext_vector_type(4))) float float4v;

__device__ inline unsigned short f2b(float f) {
  union { float f; unsigned u; } v; v.f = f;
  unsigned u = v.u;
  return (unsigned short)((u + 0x7fffu + ((u >> 16) & 1u)) >> 16);  // RNE
}

__device__ inline void gload_lds16(const void* g, void* l) {
  __builtin_amdgcn_global_load_lds(
      (const __attribute__((address_space(1))) void*)g,
      (__attribute__((address_space(3))) void*)l, 16, 0, 0);
}

#define MFMA16(a, b, c) __builtin_amdgcn_mfma_f32_16x16x32_bf16((a), (b), (c), 0, 0, 0)

// ---------------- bucketing (contention-free counting sort) ----------------
// pass 1: per-block LDS histogram -> blockhist[b][16]
__global__ void hist_k(const int* __restrict__ cat, int* __restrict__ blockhist) {
  __shared__ int h[CC];
  const int tid = threadIdx.x;
  if (tid < CC) h[tid] = 0;
  __syncthreads();
  const int i = blockIdx.x * 256 + tid;
  atomicAdd(&h[cat[i]], 1);
  __syncthreads();
  if (tid < CC) blockhist[blockIdx.x * CC + tid] = h[tid];
}

// pass 2: one block. counts, padded category offsets, per-block bases.
__global__ void offsets2_k(const int* __restrict__ blockhist,
                           int* __restrict__ counts, int* __restrict__ padoff,
                           int* __restrict__ base) {
  __shared__ int part[CC][64];
  __shared__ int pref[CC][64];
  __shared__ int scnt[CC];
  __shared__ int spad[CC + 1];
  const int tid = threadIdx.x;       // 1024 threads
  const int c = tid >> 6;            // 0..15
  const int g = tid & 63;            // 0..63, each handles 8 blocks
  int h[8];
  int s = 0;
#pragma unroll
  for (int i = 0; i < 8; i++) {
    h[i] = blockhist[(g * 8 + i) * CC + c];
    s += h[i];
  }
  part[c][g] = s;
  __syncthreads();
  if (g == 0) {
    int r = 0;
    for (int j = 0; j < 64; j++) { pref[c][j] = r; r += part[c][j]; }
    scnt[c] = r;
  }
  __syncthreads();
  if (tid == 0) {
    int acc = 0;
    for (int c2 = 0; c2 < CC; c2++) {
      spad[c2] = acc;
      padoff[c2] = acc;
      counts[c2] = scnt[c2];
      acc += ((scnt[c2] + TM - 1) / TM) * TM;
    }
    spad[CC] = acc;
    padoff[CC] = acc;
  }
  __syncthreads();
  int run = spad[c] + pref[c][g];
#pragma unroll
  for (int i = 0; i < 8; i++) {
    base[(g * 8 + i) * CC + c] = run;
    run += h[i];
  }
}

// pass 3: scatter with LDS cursors (no global atomics)
__global__ void scatter2_k(const int* __restrict__ cat, const int* __restrict__ base,
                           int* __restrict__ idx) {
  __shared__ int cur[CC];
  const int tid = threadIdx.x;
  if (tid < CC) cur[tid] = base[blockIdx.x * CC + tid];
  __syncthreads();
  const int i = blockIdx.x * 256 + tid;
  const int c = cat[i];
  const int pos = atomicAdd(&cur[c], 1);
  idx[pos] = i;
}

// ---------------- weight conversion (f32 -> bf16, transposed [c][n][k], pre-swizzled) ----------------
// W1 src: [c][k=256][n=1024] -> dst rows (c*1024+n)*512 bytes, chunk byte (k*2)^((n&7)<<4)
__global__ void conv_w1_k(const float* __restrict__ W1, short* __restrict__ w1b) {
  int t = blockIdx.x * blockDim.x + threadIdx.x;   // 524288 threads
  int n = t & 1023;
  int j = (t >> 10) & 31;   // k-chunk of 8
  int c = t >> 15;
  const float* src = W1 + (size_t)c * 256 * 1024;
  bf16x8 o;
#pragma unroll
  for (int i = 0; i < 8; i++)
    o[i] = (short)f2b(src[(size_t)(j * 8 + i) * 1024 + n]);
  char* dst = (char*)w1b + (size_t)(c * 1024 + n) * 512 + ((j * 16) ^ ((n & 7) << 4));
  *(bf16x8*)dst = o;
}

// W2 src: [c][k=1024][n=256] -> dst rows (c*256+n)*2048 bytes, chunk byte (k*2)^((n&7)<<4)
__global__ void conv_w2_k(const float* __restrict__ W2, short* __restrict__ w2b) {
  int t = blockIdx.x * blockDim.x + threadIdx.x;   // 524288 threads
  int n = t & 255;
  int j = (t >> 8) & 127;   // k-chunk of 8
  int c = t >> 15;
  const float* src = W2 + (size_t)c * 1024 * 256;
  bf16x8 o;
#pragma unroll
  for (int i = 0; i < 8; i++)
    o[i] = (short)f2b(src[(size_t)(j * 8 + i) * 256 + n]);
  char* dst = (char*)w2b + (size_t)(c * 256 + n) * 2048 + ((j * 16) ^ ((n & 7) << 4));
  *(bf16x8*)dst = o;
}

// ---------------- fused routed MLP ----------------
// wg: 512 thr (8 waves, 4x2 wave grid), tile = 128 tokens.
// loop 16 hidden blocks of 64: L1 [128x256]x[256x64] -> relu -> hs ; L2 acc += [128x64]x[64x256]
__launch_bounds__(512, 2)
__global__ void mlp_k(const float* __restrict__ x,
                      const float* __restrict__ b1,
                      const float* __restrict__ b2,
                      const short* __restrict__ w1b,
                      const short* __restrict__ w2b,
                      const int* __restrict__ idx,
                      const int* __restrict__ padoff,
                      const int* __restrict__ counts,
                      float* __restrict__ out) {
  __shared__ __align__(16) short xs[TM * 256];   // 64 KB, [r][k] rows 512B, swz ((r&7)<<4)
  __shared__ __align__(16) short w1s[64 * 256];  // 32 KB, [n][k] rows 512B, swz ((n&7)<<4)
  __shared__ __align__(16) short w2s[256 * 64];  // 32 KB, [n][kloc] rows 128B, swz ((n&7)<<4)
  __shared__ __align__(16) short hs[TM * 64];    // 16 KB, [r][kloc] rows 128B, swz ((r&7)<<4)
  __shared__ int toks[TM];

  const int p = blockIdx.x * TM;                 // padded global position
  const int total = padoff[CC];
  if (p >= total) return;
  int c = 0;
  while (padoff[c + 1] <= p) c++;
  const int cnt = counts[c];
  const int start = p - padoff[c];

  const int tid  = threadIdx.x;
  const int lane = tid & 63;
  const int w    = tid >> 6;   // 0..7
  const int wm   = w >> 1;     // 0..3  (M: 32 rows each)
  const int wn   = w & 1;      // 0..1
  const int lrow = lane & 15;
  const int lgrp = lane >> 4;

  // ---- stage x tile (gather, f32 -> bf16) + toks ----
  {
    const int r = tid >> 2;      // 0..127
    const int q = tid & 3;       // column quarter (64 f32 each)
    const int pos = start + r;
    int tok = -1;
    if (pos < cnt) tok = idx[p + r];
    if (q == 0) toks[r] = tok;
    const int swz = (r & 7) << 4;
    char* rowbase = (char*)xs + r * 512;
    if (tok >= 0) {
      const float4v* src = (const float4v*)(x + (size_t)tok * DIN) + q * 16;
#pragma unroll
      for (int j = 0; j < 8; j++) {
        float4v v0 = src[2 * j];
        float4v v1 = src[2 * j + 1];
        bf16x8 o;
        o[0] = (short)f2b(v0[0]); o[1] = (short)f2b(v0[1]);
        o[2] = (short)f2b(v0[2]); o[3] = (short)f2b(v0[3]);
        o[4] = (short)f2b(v1[0]); o[5] = (short)f2b(v1[1]);
        o[6] = (short)f2b(v1[2]); o[7] = (short)f2b(v1[3]);
        *(bf16x8*)(rowbase + ((q * 128 + j * 16) ^ swz)) = o;
      }
    } else {
      bf16x8 z = {0, 0, 0, 0, 0, 0, 0, 0};
#pragma unroll
      for (int j = 0; j < 8; j++)
        *(bf16x8*)(rowbase + ((q * 128 + j * 16) ^ swz)) = z;
    }
  }
  __syncthreads();

  f32x4 acc2[2][8];
#pragma unroll
  for (int mi = 0; mi < 2; mi++)
#pragma unroll
    for (int ni = 0; ni < 8; ni++)
      acc2[mi][ni] = (f32x4){0.f, 0.f, 0.f, 0.f};

  const char* w1g = (const char*)w1b + (size_t)c * 1024 * 512;
  const char* w2g = (const char*)w2b + (size_t)c * 256 * 2048;

  for (int hb = 0; hb < 16; hb++) {
    // ---- stage W1 block (contiguous 32KB) + W2 block (strided rows) ----
    {
      const char* src1 = w1g + (size_t)hb * 32768;
#pragma unroll
      for (int i = 0; i < 4; i++) {
        int chunk = (w * 4 + i) * 1024;
        gload_lds16(src1 + chunk + lane * 16, (char*)w1s + chunk);
      }
#pragma unroll
      for (int i = 0; i < 4; i++) {
        int o = (w * 4 + i) * 1024 + lane * 16;
        int n = o >> 7;          // 128 B per n-row
        int q = o & 127;
        gload_lds16(w2g + (size_t)n * 2048 + hb * 128 + q, (char*)w2s + (w * 4 + i) * 1024);
      }
    }
    asm volatile("s_waitcnt vmcnt(0)" ::: "memory");
    __syncthreads();

    // ---- layer 1: acc1 = x_tile @ W1blk ----
    f32x4 acc1[2][2];
#pragma unroll
    for (int mi = 0; mi < 2; mi++)
#pragma unroll
      for (int ni = 0; ni < 2; ni++)
        acc1[mi][ni] = (f32x4){0.f, 0.f, 0.f, 0.f};

#pragma unroll
    for (int ks = 0; ks < 8; ks++) {
      const int kb = ks * 64 + lgrp * 16;
      bf16x8 a[2], bf[2];
#pragma unroll
      for (int mi = 0; mi < 2; mi++) {
        int r = wm * 32 + mi * 16 + lrow;
        a[mi] = *(const bf16x8*)((const char*)xs + r * 512 + (kb ^ ((r & 7) << 4)));
      }
#pragma unroll
      for (int ni = 0; ni < 2; ni++) {
        int n = wn * 32 + ni * 16 + lrow;
        bf[ni] = *(const bf16x8*)((const char*)w1s + n * 512 + (kb ^ ((n & 7) << 4)));
      }
#pragma unroll
      for (int mi = 0; mi < 2; mi++)
#pragma unroll
        for (int ni = 0; ni < 2; ni++)
          acc1[mi][ni] = MFMA16(a[mi], bf[ni], acc1[mi][ni]);
    }

    // ---- bias + relu -> hs (bf16) ----
#pragma unroll
    for (int mi = 0; mi < 2; mi++) {
#pragma unroll
      for (int ni = 0; ni < 2; ni++) {
        int ncol = wn * 32 + ni * 16 + lrow;   // 0..63
        float b1v = b1[(size_t)c * DH + hb * 64 + ncol];
#pragma unroll
        for (int jj = 0; jj < 4; jj++) {
          int r = wm * 32 + mi * 16 + lgrp * 4 + jj;
          float v = acc1[mi][ni][jj] + b1v;
          v = fmaxf(v, 0.0f);
          *(short*)((char*)hs + r * 128 + ((ncol * 2) ^ ((r & 7) << 4))) = (short)f2b(v);
        }
      }
    }
    __syncthreads();

    // ---- layer 2: acc2 += hs @ W2blk ----
#pragma unroll
    for (int ks = 0; ks < 2; ks++) {
      const int kb = ks * 64 + lgrp * 16;
      bf16x8 a[2];
#pragma unroll
      for (int mi = 0; mi < 2; mi++) {
        int r = wm * 32 + mi * 16 + lrow;
        a[mi] = *(const bf16x8*)((const char*)hs + r * 128 + (kb ^ ((r & 7) << 4)));
      }
#pragma unroll
      for (int ni = 0; ni < 8; ni++) {
        int n = wn * 128 + ni * 16 + lrow;    // 0..255
        bf16x8 bf = *(const bf16x8*)((const char*)w2s + n * 128 + (kb ^ ((n & 7) << 4)));
#pragma unroll
        for (int mi = 0; mi < 2; mi++)
          acc2[mi][ni] = MFMA16(a[mi], bf, acc2[mi][ni]);
      }
    }
    __syncthreads();
  }

  // ---- epilogue: + b2, scatter to out ----
#pragma unroll
  for (int ni = 0; ni < 8; ni++) {
    int col = wn * 128 + ni * 16 + lrow;
    float b2v = b2[(size_t)c * DOUT + col];
#pragma unroll
    for (int mi = 0; mi < 2; mi++) {
#pragma unroll
      for (int jj = 0; jj < 4; jj++) {
        int r = wm * 32 + mi * 16 + lgrp * 4 + jj;
        int tok = toks[r];
        if (tok >= 0) out[(size_t)tok * DOUT + col] = acc2[mi][ni][jj] + b2v;
      }
    }
  }
}

extern "C" void kernel_launch(void* const* d_in, const int* in_sizes, int n_in,
                              void* d_out, int out_size, void* d_ws, size_t ws_size,
                              hipStream_t stream) {
  (void)in_sizes; (void)n_in; (void)out_size; (void)ws_size;
  const float* x   = (const float*)d_in[0];
  const int*   cat = (const int*)d_in[1];
  const float* W1  = (const float*)d_in[2];
  const float* b1  = (const float*)d_in[3];
  const float* W2  = (const float*)d_in[4];
  const float* b2  = (const float*)d_in[5];
  float* out = (float*)d_out;

  char* ws = (char*)d_ws;
  int* counts    = (int*)(ws);
  int* padoff    = (int*)(ws + 128);
  int* blockhist = (int*)(ws + 4096);                   // NB*CC ints = 32 KB
  int* base      = (int*)(ws + 65536);                  // NB*CC ints = 32 KB
  int* idx       = (int*)(ws + 131072);                 // (BB + CC*TM) ints
  short* w1b     = (short*)(ws + (1 << 20));            // 8 MB  [c][n=1024][k=256] bf16 swz
  short* w2b     = (short*)(ws + (1 << 20) + 8388608);  // 8 MB  [c][n=256][k=1024] bf16 swz

  hist_k<<<NB, 256, 0, stream>>>(cat, blockhist);
  offsets2_k<<<1, 1024, 0, stream>>>(blockhist, counts, padoff, base);
  scatter2_k<<<NB, 256, 0, stream>>>(cat, base, idx);
  conv_w1_k<<<2048, 256, 0, stream>>>(W1, w1b);
  conv_w2_k<<<2048, 256, 0, stream>>>(W2, w2b);

  const int ntiles = BB / TM + CC;   // upper bound incl. per-category padding
  mlp_k<<<ntiles, 512, 0, stream>>>(x, b1, b2, w1b, w2b, idx, padoff, counts, out);
}

// Round 3
// 267.387 us; speedup vs baseline: 3.9722x; 1.3363x over previous
//
#include <hip/hip_runtime.h>
#include <hip/hip_bf16.h>

#define BB   131072
#define CC   16
#define DIN  256
#define DH   1024
#define DOUT 256
#define TM   128   // tokens per tile
#define NB   512   // bucketing blocks (BB/NB = 256 tokens each)

typedef __attribute__((ext_vector_type(8))) short bf16x8;
typedef __attribute__((ext_vector_type(4))) short short4v;
typedef __attribute__((ext_vector_type(4))) float f32x4;
typedef __attribute__((ext_vector_type(4))) float float4v;

__device__ inline unsigned short f2b(float f) {
  union { float f; unsigned u; } v; v.f = f;
  unsigned u = v.u;
  return (unsigned short)((u + 0x7fffu + ((u >> 16) & 1u)) >> 16);  // RNE
}

__device__ inline void gload_lds16(const void* g, void* l) {
  __builtin_amdgcn_global_load_lds(
      (const __attribute__((address_space(1))) void*)g,
      (__attribute__((address_space(3))) void*)l, 16, 0, 0);
}

#define MFMA16(a, b, c) __builtin_amdgcn_mfma_f32_16x16x32_bf16((a), (b), (c), 0, 0, 0)

// ---------------- bucketing (contention-free counting sort) ----------------
__global__ void hist_k(const int* __restrict__ cat, int* __restrict__ blockhist) {
  __shared__ int h[CC];
  const int tid = threadIdx.x;
  if (tid < CC) h[tid] = 0;
  __syncthreads();
  const int i = blockIdx.x * 256 + tid;
  atomicAdd(&h[cat[i]], 1);
  __syncthreads();
  if (tid < CC) blockhist[blockIdx.x * CC + tid] = h[tid];
}

__global__ void offsets2_k(const int* __restrict__ blockhist,
                           int* __restrict__ counts, int* __restrict__ padoff,
                           int* __restrict__ base) {
  __shared__ int part[CC][64];
  __shared__ int pref[CC][64];
  __shared__ int scnt[CC];
  __shared__ int spad[CC + 1];
  const int tid = threadIdx.x;       // 1024 threads
  const int c = tid >> 6;
  const int g = tid & 63;
  int h[8];
  int s = 0;
#pragma unroll
  for (int i = 0; i < 8; i++) {
    h[i] = blockhist[(g * 8 + i) * CC + c];
    s += h[i];
  }
  part[c][g] = s;
  __syncthreads();
  if (g == 0) {
    int r = 0;
    for (int j = 0; j < 64; j++) { pref[c][j] = r; r += part[c][j]; }
    scnt[c] = r;
  }
  __syncthreads();
  if (tid == 0) {
    int acc = 0;
    for (int c2 = 0; c2 < CC; c2++) {
      spad[c2] = acc;
      padoff[c2] = acc;
      counts[c2] = scnt[c2];
      acc += ((scnt[c2] + TM - 1) / TM) * TM;
    }
    spad[CC] = acc;
    padoff[CC] = acc;
  }
  __syncthreads();
  int run = spad[c] + pref[c][g];
#pragma unroll
  for (int i = 0; i < 8; i++) {
    base[(g * 8 + i) * CC + c] = run;
    run += h[i];
  }
}

__global__ void scatter2_k(const int* __restrict__ cat, const int* __restrict__ base,
                           int* __restrict__ idx) {
  __shared__ int cur[CC];
  const int tid = threadIdx.x;
  if (tid < CC) cur[tid] = base[blockIdx.x * CC + tid];
  __syncthreads();
  const int i = blockIdx.x * 256 + tid;
  const int c = cat[i];
  const int pos = atomicAdd(&cur[c], 1);
  idx[pos] = i;
}

// ---------------- weight conversion (f32 -> bf16, transposed [c][n][k], pre-swizzled) ----------------
__global__ void conv_w1_k(const float* __restrict__ W1, short* __restrict__ w1b) {
  int t = blockIdx.x * blockDim.x + threadIdx.x;
  int n = t & 1023;
  int j = (t >> 10) & 31;
  int c = t >> 15;
  const float* src = W1 + (size_t)c * 256 * 1024;
  bf16x8 o;
#pragma unroll
  for (int i = 0; i < 8; i++)
    o[i] = (short)f2b(src[(size_t)(j * 8 + i) * 1024 + n]);
  char* dst = (char*)w1b + (size_t)(c * 1024 + n) * 512 + ((j * 16) ^ ((n & 7) << 4));
  *(bf16x8*)dst = o;
}

__global__ void conv_w2_k(const float* __restrict__ W2, short* __restrict__ w2b) {
  int t = blockIdx.x * blockDim.x + threadIdx.x;
  int n = t & 255;
  int j = (t >> 8) & 127;
  int c = t >> 15;
  const float* src = W2 + (size_t)c * 1024 * 256;
  bf16x8 o;
#pragma unroll
  for (int i = 0; i < 8; i++)
    o[i] = (short)f2b(src[(size_t)(j * 8 + i) * 256 + n]);
  char* dst = (char*)w2b + (size_t)(c * 256 + n) * 2048 + ((j * 16) ^ ((n & 7) << 4));
  *(bf16x8*)dst = o;
}

// ---------------- fused routed MLP ----------------
// 512 thr (8 waves: wt = w&3 over tokens, wh = w>>2 over n). Tile = 128 tokens.
// A = weights, B = activations, D = [n][token] fragments.
// LDS: w1s dbuf 2x32K @0 | w2s dbuf 2x32K @64K | hs 16K @128K | toks @144K | b1s @~144.5K | b2s
#define W2OFF  65536
#define HSOFF  131072
#define TKOFF  147456
#define B1OFF  147968
#define B2OFF  152064

__launch_bounds__(512, 2)
__global__ void mlp_k(const float* __restrict__ x,
                      const float* __restrict__ b1,
                      const float* __restrict__ b2,
                      const short* __restrict__ w1b,
                      const short* __restrict__ w2b,
                      const int* __restrict__ idx,
                      const int* __restrict__ padoff,
                      const int* __restrict__ counts,
                      float* __restrict__ out) {
  __shared__ __align__(16) char sm[153088];

  const int bhw = blockIdx.x;
  const int wg = (bhw & 7) * 130 + (bhw >> 3);   // XCD-chunked swizzle, 1040 = 8*130
  const int p = wg * TM;
  const int total = padoff[CC];
  if (p >= total) return;
  int c = 0;
  while (padoff[c + 1] <= p) c++;
  const int cnt = counts[c];
  const int start = p - padoff[c];

  const int tid  = threadIdx.x;
  const int lane = tid & 63;
  const int w    = tid >> 6;   // 0..7
  const int wt   = w & 3;      // token group (32 each)
  const int wh   = w >> 2;     // 0..1: L1 n-group (32), L2 n-group (128)
  const int lrow = lane & 15;
  const int lgrp = lane >> 4;

  char* hsb   = sm + HSOFF;
  int*  toksp = (int*)(sm + TKOFF);
  float* b1s  = (float*)(sm + B1OFF);
  float* b2s  = (float*)(sm + B2OFF);

  // ---- prologue: gather x (f32->bf16, swizzled) into sm[0..64K), toks, biases ----
  {
    const int r = tid >> 2;      // 0..127
    const int q = tid & 3;       // 64-float quarter
    const int pos = start + r;
    int tok = -1;
    if (pos < cnt) tok = idx[p + r];
    if (q == 0) toksp[r] = tok;
    const int swz = (r & 7) << 4;
    char* rowbase = sm + r * 512;
    if (tok >= 0) {
      const float4v* src = (const float4v*)(x + (size_t)tok * DIN) + q * 16;
#pragma unroll
      for (int j = 0; j < 8; j++) {
        float4v v0 = src[2 * j];
        float4v v1 = src[2 * j + 1];
        bf16x8 o;
        o[0] = (short)f2b(v0[0]); o[1] = (short)f2b(v0[1]);
        o[2] = (short)f2b(v0[2]); o[3] = (short)f2b(v0[3]);
        o[4] = (short)f2b(v1[0]); o[5] = (short)f2b(v1[1]);
        o[6] = (short)f2b(v1[2]); o[7] = (short)f2b(v1[3]);
        *(bf16x8*)(rowbase + ((q * 128 + j * 16) ^ swz)) = o;
      }
    } else {
      bf16x8 z = {0, 0, 0, 0, 0, 0, 0, 0};
#pragma unroll
      for (int j = 0; j < 8; j++)
        *(bf16x8*)(rowbase + ((q * 128 + j * 16) ^ swz)) = z;
    }
    if (tid < 256) ((f32x4*)b1s)[tid] = ((const f32x4*)(b1 + (size_t)c * DH))[tid];
    if (tid < 64)  ((f32x4*)b2s)[tid] = ((const f32x4*)(b2 + (size_t)c * DOUT))[tid];
  }
  __syncthreads();

  // ---- x fragments to registers: xf[ti][ks] (B-operand: col=token, k slice) ----
  bf16x8 xf[2][8];
#pragma unroll
  for (int ti = 0; ti < 2; ti++) {
    const int r = wt * 32 + ti * 16 + lrow;
    const int swz = (r & 7) << 4;
#pragma unroll
    for (int ks = 0; ks < 8; ks++)
      xf[ti][ks] = *(const bf16x8*)(sm + r * 512 + ((ks * 64 + lgrp * 16) ^ swz));
  }
  __syncthreads();   // xs region now free for weight buffers

  const char* w1g = (const char*)w1b + (size_t)c * 1024 * 512;
  const char* w2g = (const char*)w2b + (size_t)c * 256 * 2048;

  auto stage1 = [&](int i) {
    const char* src = w1g + (size_t)i * 32768;
    char* dst = sm + (i & 1) * 32768;
#pragma unroll
    for (int j = 0; j < 4; j++) {
      int chunk = (w * 4 + j) * 1024;
      gload_lds16(src + chunk + lane * 16, dst + chunk);
    }
  };
  auto stage2 = [&](int i) {
    char* dst = sm + W2OFF + (i & 1) * 32768;
#pragma unroll
    for (int j = 0; j < 4; j++) {
      int o = (w * 4 + j) * 1024 + lane * 16;
      int n = o >> 7;
      int q = o & 127;
      gload_lds16(w2g + (size_t)n * 2048 + i * 128 + q, dst + (w * 4 + j) * 1024);
    }
  };

  stage1(0);
  stage2(0);
  __syncthreads();   // full drain (prologue only): buffers 0 ready

  f32x4 acc2[8][2];
#pragma unroll
  for (int ni = 0; ni < 8; ni++)
#pragma unroll
    for (int ti = 0; ti < 2; ti++)
      acc2[ni][ti] = (f32x4){0.f, 0.f, 0.f, 0.f};

  for (int hb = 0; hb < 16; hb++) {
    const char* w1c = sm + (hb & 1) * 32768;
    const char* w2c = sm + W2OFF + (hb & 1) * 32768;

    // ================= region A: L1 (32 MFMA) + bias/relu/pack -> hs =================
    f32x4 acc1[2][2];
#pragma unroll
    for (int ni = 0; ni < 2; ni++)
#pragma unroll
      for (int ti = 0; ti < 2; ti++)
        acc1[ni][ti] = (f32x4){0.f, 0.f, 0.f, 0.f};

#pragma unroll
    for (int ks = 0; ks < 8; ks++) {
      bf16x8 a1[2];
#pragma unroll
      for (int ni = 0; ni < 2; ni++) {
        int n = wh * 32 + ni * 16 + lrow;
        a1[ni] = *(const bf16x8*)(w1c + n * 512 + ((ks * 64 + lgrp * 16) ^ ((n & 7) << 4)));
      }
#pragma unroll
      for (int ni = 0; ni < 2; ni++)
#pragma unroll
        for (int ti = 0; ti < 2; ti++)
          acc1[ni][ti] = MFMA16(a1[ni], xf[ti][ks], acc1[ni][ti]);
    }

#pragma unroll
    for (int ni = 0; ni < 2; ni++) {
      const int n0 = wh * 32 + ni * 16 + lgrp * 4;
      f32x4 bv = *(const f32x4*)(b1s + hb * 64 + n0);
#pragma unroll
      for (int ti = 0; ti < 2; ti++) {
        const int r = wt * 32 + ti * 16 + lrow;
        short4v h;
#pragma unroll
        for (int jj = 0; jj < 4; jj++) {
          float v = fmaxf(acc1[ni][ti][jj] + bv[jj], 0.0f);
          h[jj] = (short)f2b(v);
        }
        *(short4v*)(hsb + r * 128 + ((n0 * 2) ^ ((r & 7) << 4))) = h;
      }
    }
    // w2[hb] loads done (issued one region earlier); hs visible to all after barrier
    asm volatile("s_waitcnt vmcnt(0) lgkmcnt(0)" ::: "memory");
    __builtin_amdgcn_s_barrier();

    // ================= region B: L2 (32 MFMA) + stage hb+1 =================
    if (hb < 15) { stage1(hb + 1); stage2(hb + 1); }

#pragma unroll
    for (int ks = 0; ks < 2; ks++) {
      bf16x8 bh[2];
#pragma unroll
      for (int ti = 0; ti < 2; ti++) {
        int r = wt * 32 + ti * 16 + lrow;
        bh[ti] = *(const bf16x8*)(hsb + r * 128 + ((ks * 64 + lgrp * 16) ^ ((r & 7) << 4)));
      }
#pragma unroll
      for (int ni = 0; ni < 8; ni++) {
        int n = wh * 128 + ni * 16 + lrow;
        bf16x8 a2 = *(const bf16x8*)(w2c + n * 128 + ((ks * 64 + lgrp * 16) ^ ((n & 7) << 4)));
#pragma unroll
        for (int ti = 0; ti < 2; ti++)
          acc2[ni][ti] = MFMA16(a2, bh[ti], acc2[ni][ti]);
      }
    }
    // w1[hb+1] done (4 w2 loads still in flight); hs reads done before rewrite
    asm volatile("s_waitcnt vmcnt(4) lgkmcnt(0)" ::: "memory");
    __builtin_amdgcn_s_barrier();
  }

  // ---- epilogue: + b2, vectorized scatter ----
#pragma unroll
  for (int ni = 0; ni < 8; ni++) {
    const int n0 = wh * 128 + ni * 16 + lgrp * 4;
    f32x4 bv = *(const f32x4*)(b2s + n0);
#pragma unroll
    for (int ti = 0; ti < 2; ti++) {
      const int rr = wt * 32 + ti * 16 + lrow;
      const int tok = toksp[rr];
      if (tok >= 0) {
        f32x4 v = acc2[ni][ti] + bv;
        *(f32x4*)(out + (size_t)tok * DOUT + n0) = v;
      }
    }
  }
}

extern "C" void kernel_launch(void* const* d_in, const int* in_sizes, int n_in,
                              void* d_out, int out_size, void* d_ws, size_t ws_size,
                              hipStream_t stream) {
  (void)in_sizes; (void)n_in; (void)out_size; (void)ws_size;
  const float* x   = (const float*)d_in[0];
  const int*   cat = (const int*)d_in[1];
  const float* W1  = (const float*)d_in[2];
  const float* b1  = (const float*)d_in[3];
  const float* W2  = (const float*)d_in[4];
  const float* b2  = (const float*)d_in[5];
  float* out = (float*)d_out;

  char* ws = (char*)d_ws;
  int* counts    = (int*)(ws);
  int* padoff    = (int*)(ws + 128);
  int* blockhist = (int*)(ws + 4096);
  int* base      = (int*)(ws + 65536);
  int* idx       = (int*)(ws + 131072);
  short* w1b     = (short*)(ws + (1 << 20));
  short* w2b     = (short*)(ws + (1 << 20) + 8388608);

  hist_k<<<NB, 256, 0, stream>>>(cat, blockhist);
  offsets2_k<<<1, 1024, 0, stream>>>(blockhist, counts, padoff, base);
  scatter2_k<<<NB, 256, 0, stream>>>(cat, base, idx);
  conv_w1_k<<<2048, 256, 0, stream>>>(W1, w1b);
  conv_w2_k<<<2048, 256, 0, stream>>>(W2, w2b);

  const int ntiles = BB / TM + CC;   // 1040 = 8 * 130 (swizzle assumes this)
  mlp_k<<<ntiles, 512, 0, stream>>>(x, b1, b2, w1b, w2b, idx, padoff, counts, out);
}